// Round 10
// baseline (39.872 us; speedup 1.0000x reference)
//
#include <hip/hip_runtime.h>

// PSRoIPool: features (B=2, C=1029, H=100, W=100) f32, rois (R=512, 5) f32.
// Output: (R, D=21, P=7, P=7) f32;  out[r*1029 + ch], ch=(d*7+ph)*7+pw.
//
// Correctness-critical (round 7): window bounds must match XLA-CPU fast-math:
// bin = roi * float(1/7) (reciprocal multiply, NOT true divide), then
// fmaf(p, bin, s). Changing either re-breaks the knife-edge ROI (absmax 0.6).
//
// Perf (round 10): wave-cooperative gather. Windows are provably <= 4x4
// (wh<=316 => bin<=2.83 => ceil-floor span <=4). 16 lanes cover one ROI's
// predicated 4x4 window (4 rows x 4 CONTIGUOUS cols => <=16 lines/wave-load
// instead of 64), 4 ROIs per wave, one load instruction per ROI, zero
// divergent loops. Tree-reduce via 4 shfl_xor steps (value-order noise only;
// bounds stay bit-exact).

#define POOLED 7
#define GROUP 7
#define OUT_DIM 21
#define FH 100
#define FW 100
#define NCH (OUT_DIM * GROUP * GROUP)  // 1029
#define PLANE (FH * FW)                // 10000
#define PER_ROI NCH

__device__ __forceinline__ float fbar(float x) { asm volatile("" : "+v"(x)); return x; }

__global__ __launch_bounds__(256) void psroi_wave_kernel(
    const float* __restrict__ feat,
    const float* __restrict__ rois,
    float* __restrict__ out,
    int R)
{
    const int ch   = blockIdx.x;           // 0..1028
    const int tid  = threadIdx.x;
    const int wave = tid >> 6;             // 0..3
    const int lane = tid & 63;
    const int grp  = lane >> 4;            // 0..3 : ROI within wave
    const int sub  = lane & 15;            // 0..15: element of 4x4 window
    const int hh   = sub >> 2;
    const int ww   = sub & 3;

    const int pw = ch % GROUP;
    const int ph = (ch / GROUP) % GROUP;

    const float rcp7  = 1.0f / 7.0f;
    const float scale = 0.0625f;
    const float phf = (float)ph;
    const float pwf = (float)pw;

    const float* p0 = feat + (size_t)ch * PLANE;           // b=0 plane
    const float* p1 = feat + ((size_t)NCH + ch) * PLANE;   // b=1 plane

    // wave handles ROIs {rbase+grp}, rbase advancing by 16 (4 waves x 4 ROIs)
    for (int rbase = wave * 4; rbase < R; rbase += 16) {
        int r = rbase + grp;
        const float* roi = rois + (size_t)r * 5;
        int b = (int)roi[0];

        // exact f32 (multiples of 2^-4 < 128):
        float sw = rintf(roi[1]) * scale;
        float sh = rintf(roi[2]) * scale;
        float ew = (rintf(roi[3]) + 1.0f) * scale;
        float eh = (rintf(roi[4]) + 1.0f) * scale;
        float roi_w = fmaxf(ew - sw, 0.1f);
        float roi_h = fmaxf(eh - sh, 0.1f);

        // XLA-CPU fast-math semantics: reciprocal multiply + fused mul-add
        float bin_w = fbar(roi_w * rcp7);
        float bin_h = fbar(roi_h * rcp7);
        float th0 = __builtin_fmaf(phf,        bin_h, sh);
        float th1 = __builtin_fmaf(phf + 1.0f, bin_h, sh);
        float tw0 = __builtin_fmaf(pwf,        bin_w, sw);
        float tw1 = __builtin_fmaf(pwf + 1.0f, bin_w, sw);

        int hs = (int)fminf(fmaxf(floorf(th0), 0.0f), (float)FH);
        int he = (int)fminf(fmaxf(ceilf(th1),  0.0f), (float)FH);
        int ws = (int)fminf(fmaxf(floorf(tw0), 0.0f), (float)FW);
        int we = (int)fminf(fmaxf(ceilf(tw1),  0.0f), (float)FW);

        int H  = he - hs;
        int Wd = we - ws;

        // predicated 4x4 window element for this lane
        int h = hs + hh;
        int w = ws + ww;
        bool valid = (hh < H) && (ww < Wd);
        int hc = min(h, FH - 1);
        int wc = min(w, FW - 1);
        const float* p = b ? p1 : p0;
        float v = p[hc * FW + wc];            // single gather, <=16 lines/wave
        float s = valid ? v : 0.0f;

        // 16-lane tree reduction
        s += __shfl_xor(s, 1);
        s += __shfl_xor(s, 2);
        s += __shfl_xor(s, 4);
        s += __shfl_xor(s, 8);

        if (sub == 0) {
            int area = H * Wd;
            out[(size_t)r * PER_ROI + ch] = (area > 0) ? s / (float)area : 0.0f;
        }
    }
}

extern "C" void kernel_launch(void* const* d_in, const int* in_sizes, int n_in,
                              void* d_out, int out_size, void* d_ws, size_t ws_size,
                              hipStream_t stream) {
    const float* feat = (const float*)d_in[0];
    const float* rois = (const float*)d_in[1];
    float* out = (float*)d_out;
    int R = in_sizes[1] / 5;  // 512
    psroi_wave_kernel<<<NCH, 256, 0, stream>>>(feat, rois, out, R);
}

// Round 11
// 26.981 us; speedup vs baseline: 1.4778x; 1.4778x over previous
//
#include <hip/hip_runtime.h>

// PSRoIPool: features (B=2, C=1029, H=100, W=100) f32, rois (R=512, 5) f32.
// Output: (R, D=21, P=7, P=7) f32;  out[r*1029 + ch], ch=(d*7+ph)*7+pw.
//
// Correctness-critical (round 7): window bounds must match XLA-CPU fast-math:
// bin = roi * float(1/7) (reciprocal multiply, NOT true divide), then
// fmaf(p, bin, s). Changing either re-breaks the knife-edge ROI (absmax 0.6).
//
// Perf (round 11): r9 structure (block/channel, thread/ROI — min fetch, no
// redundant VALU) + float4 row loads. Windows are <=4x4, so each row is one
// dword-aligned dwordx4 (clamped start wl=min(ws,96), element masks) —
// 4 predicated vector loads replace 16 divergent scalar loads per (r,ch).
// r10 post-mortem: 16-lane coop doubled FETCH (83MB) + 16x redundant bound
// VALU (27% busy) => regressed; this keeps r9's traffic shape instead.

#define POOLED 7
#define GROUP 7
#define OUT_DIM 21
#define FH 100
#define FW 100
#define NCH (OUT_DIM * GROUP * GROUP)  // 1029
#define PLANE (FH * FW)                // 10000
#define PER_ROI NCH

typedef float f4 __attribute__((ext_vector_type(4)));
typedef f4 __attribute__((aligned(4))) f4u;   // dword-aligned vector load

__device__ __forceinline__ float fbar(float x) { asm volatile("" : "+v"(x)); return x; }

__global__ __launch_bounds__(256) void psroi_f4_kernel(
    const float* __restrict__ feat,
    const float* __restrict__ rois,
    float* __restrict__ out,
    int R)
{
    const int ch  = blockIdx.x;          // 0..1028
    const int tid = threadIdx.x;

    const int pw = ch % GROUP;
    const int ph = (ch / GROUP) % GROUP;

    const float rcp7  = 1.0f / 7.0f;
    const float scale = 0.0625f;
    const float phf = (float)ph;
    const float pwf = (float)pw;

    const float* p0 = feat + (size_t)ch * PLANE;           // b=0 plane
    const float* p1 = feat + ((size_t)NCH + ch) * PLANE;   // b=1 plane

    for (int r = tid; r < R; r += 256) {
        const float* roi = rois + (size_t)r * 5;
        int b = (int)roi[0];

        // exact f32 (multiples of 2^-4 < 128):
        float sw = rintf(roi[1]) * scale;
        float sh = rintf(roi[2]) * scale;
        float ew = (rintf(roi[3]) + 1.0f) * scale;
        float eh = (rintf(roi[4]) + 1.0f) * scale;
        float roi_w = fmaxf(ew - sw, 0.1f);
        float roi_h = fmaxf(eh - sh, 0.1f);

        // XLA-CPU fast-math semantics: reciprocal multiply + fused mul-add
        float bin_w = fbar(roi_w * rcp7);
        float bin_h = fbar(roi_h * rcp7);
        float th0 = __builtin_fmaf(phf,        bin_h, sh);
        float th1 = __builtin_fmaf(phf + 1.0f, bin_h, sh);
        float tw0 = __builtin_fmaf(pwf,        bin_w, sw);
        float tw1 = __builtin_fmaf(pwf + 1.0f, bin_w, sw);

        int hs = (int)fminf(fmaxf(floorf(th0), 0.0f), (float)FH);
        int he = (int)fminf(fmaxf(ceilf(th1),  0.0f), (float)FH);
        int ws = (int)fminf(fmaxf(floorf(tw0), 0.0f), (float)FW);
        int we = (int)fminf(fmaxf(ceilf(tw1),  0.0f), (float)FW);

        int H  = he - hs;                 // 0..4
        int Wd = we - ws;                 // 0..4

        int wl = min(ws, FW - 4);         // clamped row start, always in-bounds
        int j0 = ws - wl;                 // first valid element index in f4
        int j1 = j0 + Wd;                 // one past last valid
        const float* p = (b ? p1 : p0) + hs * FW + wl;

        float s = 0.0f;
        #pragma unroll
        for (int hh = 0; hh < 4; ++hh) {
            if (hh < H) {
                f4 v = *(const f4u*)(p + hh * FW);   // one dwordx4 per row
                #pragma unroll
                for (int k = 0; k < 4; ++k) {
                    s += (k >= j0 && k < j1) ? v[k] : 0.0f;
                }
            }
        }
        int area = H * Wd;
        out[(size_t)r * PER_ROI + ch] = (area > 0) ? s / (float)area : 0.0f;
    }
}

extern "C" void kernel_launch(void* const* d_in, const int* in_sizes, int n_in,
                              void* d_out, int out_size, void* d_ws, size_t ws_size,
                              hipStream_t stream) {
    const float* feat = (const float*)d_in[0];
    const float* rois = (const float*)d_in[1];
    float* out = (float*)d_out;
    int R = in_sizes[1] / 5;  // 512
    psroi_f4_kernel<<<NCH, 256, 0, stream>>>(feat, rois, out, R);
}